// Round 5
// baseline (791.759 us; speedup 1.0000x reference)
//
#include <hip/hip_runtime.h>
#include <hip/hip_cooperative_groups.h>
#include <stdint.h>

namespace cg = cooperative_groups;

// ---------------------------------------------------------------------------
// PrimitiveFitting: voxel-hash primitive fitting (mu + scaled-eigvec R).
//
// R4 post-mortem: pipeline is launch/serialization-overhead bound (11 serial
// dispatches + 31MB serial memsets ~= 90us of the 194us). R5: fuse everything
// into ONE cooperative kernel with grid.sync() phase barriers:
//   0 zero ws + minmax partials | 1 prep | 2 mark | 3 scanA | 4 scanB
//   5 probe (hit list + count atomics) | 6 drain | 7 finalize
// Multi-kernel R4 path kept as fallback if cooperative enqueue fails.
// ---------------------------------------------------------------------------

#define WMAX   5402624u       // bitmap words = 2638 * 2048  (>= 10*258^3 / 32)
#define PBLK   2638           // scan superblocks (2048 words = 65536 bits)
#define CHUNK  11             // ceil(PBLK / 256)
#define HCAP   1024           // LDS staging entries / block (expected ~280)
#define HITCAP 786432         // global hit list capacity (expected ~216k)

struct Hdr {
  float pc_min[4];
  int   dims[4];
  int   M;
};

__device__ __forceinline__ unsigned fkey_map(float f) {
  unsigned u = __float_as_uint(f);
  return (u & 0x80000000u) ? ~u : (u | 0x80000000u);
}
__device__ __forceinline__ float fkey_unmap(unsigned u) {
  unsigned b = (u & 0x80000000u) ? (u ^ 0x80000000u) : ~u;
  return __uint_as_float(b);
}

__device__ __forceinline__ void coors_from(float4 p, float pc0, float pc1,
                                           float pc2, float pc3, int c[4]) {
  // Must match numpy bitwise: f32 subtract, IEEE f32 divide, rint (half-even).
  c[0] = (int)rintf((p.x - pc0) / 1.0f) + 1;
  c[1] = (int)rintf((p.y - pc1) / 0.4f) + 1;
  c[2] = (int)rintf((p.z - pc2) / 0.4f) + 1;
  c[3] = (int)rintf((p.w - pc3) / 0.4f) + 1;
}

__device__ __forceinline__ void direct_accum(float* __restrict__ acc, int r,
                                             float wgt, float4 p) {
  float* a = acc + (size_t)r * 12;
  atomicAdd((unsigned*)(a + 11), 1u);
  atomicAdd(a + 0, wgt);
  atomicAdd(a + 1, wgt * p.x);
  atomicAdd(a + 2, wgt * p.y);
  atomicAdd(a + 3, wgt * p.z);
  atomicAdd(a + 4, wgt * p.w);
  atomicAdd(a + 5, wgt * p.y * p.y);
  atomicAdd(a + 6, wgt * p.y * p.z);
  atomicAdd(a + 7, wgt * p.y * p.w);
  atomicAdd(a + 8, wgt * p.z * p.z);
  atomicAdd(a + 9, wgt * p.z * p.w);
  atomicAdd(a + 10, wgt * p.w * p.w);
}

__device__ __forceinline__ void jacobi_out(float ws, float4 v0, float4 v1,
                                           float4 v2, bool ok,
                                           float* mu_o, float* R_o) {
  if (!ok) {
    mu_o[0] = mu_o[1] = mu_o[2] = mu_o[3] = 0.0f;
    #pragma unroll
    for (int k = 0; k < 9; ++k) R_o[k] = 0.0f;
    return;
  }
  float mu0 = v0.y / ws, mu1 = v0.z / ws, mu2 = v0.w / ws, mu3 = v1.x / ws;
  float A[3][3];
  A[0][0] = v1.y / ws - mu1 * mu1;
  A[0][1] = A[1][0] = v1.z / ws - mu1 * mu2;
  A[0][2] = A[2][0] = v1.w / ws - mu1 * mu3;
  A[1][1] = v2.x / ws - mu2 * mu2;
  A[1][2] = A[2][1] = v2.y / ws - mu2 * mu3;
  A[2][2] = v2.z / ws - mu3 * mu3;

  float V[3][3] = {{1.f, 0.f, 0.f}, {0.f, 1.f, 0.f}, {0.f, 0.f, 1.f}};
  for (int sweep = 0; sweep < 8; ++sweep) {
    #pragma unroll
    for (int pi = 0; pi < 3; ++pi) {
      int p = (pi == 2) ? 1 : 0;
      int q = (pi == 0) ? 1 : 2;
      float apq = A[p][q];
      if (apq == 0.0f) continue;
      float app = A[p][p], aqq = A[q][q];
      float theta = (aqq - app) / (2.0f * apq);
      float t = 1.0f / (fabsf(theta) + sqrtf(theta * theta + 1.0f));
      if (theta < 0.0f) t = -t;
      float cth = 1.0f / sqrtf(t * t + 1.0f);
      float sth = t * cth;
      A[p][p] = app - t * apq;
      A[q][q] = aqq + t * apq;
      A[p][q] = A[q][p] = 0.0f;
      int k = 3 - p - q;
      float akp = A[k][p], akq = A[k][q];
      A[k][p] = A[p][k] = cth * akp - sth * akq;
      A[k][q] = A[q][k] = sth * akp + cth * akq;
      #pragma unroll
      for (int r = 0; r < 3; ++r) {
        float vp = V[r][p], vq = V[r][q];
        V[r][p] = cth * vp - sth * vq;
        V[r][q] = sth * vp + cth * vq;
      }
    }
  }
  float l0 = fabsf(A[0][0]), l1 = fabsf(A[1][1]), l2 = fabsf(A[2][2]);
  float a[3] = {l0, l1, l2};
  int idx[3] = {0, 1, 2};
  if (a[idx[0]] < a[idx[1]]) { int t = idx[0]; idx[0] = idx[1]; idx[1] = t; }
  if (a[idx[1]] < a[idx[2]]) { int t = idx[1]; idx[1] = idx[2]; idx[2] = t; }
  if (a[idx[0]] < a[idx[1]]) { int t = idx[0]; idx[0] = idx[1]; idx[1] = t; }
  float S0 = fmaxf(sqrtf(a[idx[0]]), 1e-6f);
  float S1 = fmaxf(sqrtf(a[idx[1]]), 1e-6f);
  float S2 = fmaxf(sqrtf(a[idx[2]]), 1e-6f);
  float U[3][3];
  #pragma unroll
  for (int r = 0; r < 3; ++r) {
    U[r][0] = V[r][idx[0]];
    U[r][1] = V[r][idx[1]];
    U[r][2] = V[r][idx[2]];
  }
  float det = U[0][0] * (U[1][1] * U[2][2] - U[1][2] * U[2][1])
            - U[0][1] * (U[1][0] * U[2][2] - U[1][2] * U[2][0])
            + U[0][2] * (U[1][0] * U[2][1] - U[1][1] * U[2][0]);
  float f2 = (det < 0.0f) ? -1.0f : 1.0f;
  mu_o[0] = mu0; mu_o[1] = mu1; mu_o[2] = mu2; mu_o[3] = mu3;
  R_o[0] = U[0][0] * S0; R_o[1] = U[0][1] * S1; R_o[2] = U[0][2] * S2 * f2;
  R_o[3] = U[1][0] * S0; R_o[4] = U[1][1] * S1; R_o[5] = U[1][2] * S2 * f2;
  R_o[6] = U[2][0] * S0; R_o[7] = U[2][1] * S1; R_o[8] = U[2][2] * S2 * f2;
}

// ========================= fused cooperative kernel =========================
__global__ __launch_bounds__(256, 4) void k_fused(
    const float4* __restrict__ pts, int n, Hdr* hdr, unsigned* mmpart,
    unsigned* bm, unsigned short* rank16, unsigned* part, unsigned* g_cnt,
    int* hit_i, int* hit_r, float* hit_w, float* acc,
    float* out_mu, float* out_R) {
  cg::grid_group grid = cg::this_grid();
  __shared__ unsigned s_red[2048];            // prep reduce / minmax partials
  __shared__ unsigned s_scan[256];
  __shared__ int s_cnt, s_base;
  __shared__ int   s_hi[HCAP];
  __shared__ int   s_hr[HCAP];
  __shared__ float s_hw[HCAP];

  const int t = threadIdx.x;
  const int gtid = blockIdx.x * 256 + t;
  const int gridT = gridDim.x * 256;

  // ---- phase 0: zero workspace + per-block minmax partials ----
  {
    uint4 z = {0u, 0u, 0u, 0u};
    uint4* bm4 = (uint4*)bm;
    for (int i = gtid; i < (int)(WMAX / 4); i += gridT) bm4[i] = z;
    uint4* acc4 = (uint4*)acc;
    int acc4n = n * 3;                        // n*12 floats / 4
    for (int i = gtid; i < acc4n; i += gridT) acc4[i] = z;
    if (gtid == 0) *g_cnt = 0u;

    float mn[4] = { INFINITY,  INFINITY,  INFINITY,  INFINITY};
    float mx[4] = {-INFINITY, -INFINITY, -INFINITY, -INFINITY};
    for (int i = gtid; i < n; i += gridT) {
      float4 p = pts[i];
      mn[0] = fminf(mn[0], p.x); mx[0] = fmaxf(mx[0], p.x);
      mn[1] = fminf(mn[1], p.y); mx[1] = fmaxf(mx[1], p.y);
      mn[2] = fminf(mn[2], p.z); mx[2] = fmaxf(mx[2], p.z);
      mn[3] = fminf(mn[3], p.w); mx[3] = fmaxf(mx[3], p.w);
    }
    #pragma unroll
    for (int off = 32; off > 0; off >>= 1) {
      #pragma unroll
      for (int c = 0; c < 4; ++c) {
        mn[c] = fminf(mn[c], __shfl_down(mn[c], off));
        mx[c] = fmaxf(mx[c], __shfl_down(mx[c], off));
      }
    }
    int wave = t >> 6;
    if ((t & 63) == 0) {
      #pragma unroll
      for (int c = 0; c < 4; ++c) {
        s_red[wave * 8 + c]     = fkey_map(mn[c]);
        s_red[wave * 8 + 4 + c] = fkey_map(mx[c]);
      }
    }
    __syncthreads();
    if (t < 8) {
      unsigned u = s_red[t];
      #pragma unroll
      for (int w = 1; w < 4; ++w)
        u = (t < 4) ? min(u, s_red[w * 8 + t]) : max(u, s_red[w * 8 + t]);
      mmpart[blockIdx.x * 8 + t] = u;
    }
  }
  grid.sync();

  // ---- phase 1: prep (block 0 only) ----
  if (blockIdx.x == 0) {
    unsigned v[8];
    #pragma unroll
    for (int c = 0; c < 4; ++c) { v[c] = 0xFFFFFFFFu; v[4 + c] = 0u; }
    for (int b = t; b < (int)gridDim.x; b += 256) {
      #pragma unroll
      for (int c = 0; c < 4; ++c) {
        v[c] = min(v[c], mmpart[b * 8 + c]);
        v[4 + c] = max(v[4 + c], mmpart[b * 8 + 4 + c]);
      }
    }
    #pragma unroll
    for (int c = 0; c < 8; ++c) s_red[t * 8 + c] = v[c];
    __syncthreads();
    for (int off = 128; off > 0; off >>= 1) {
      if (t < off) {
        #pragma unroll
        for (int c = 0; c < 4; ++c)
          s_red[t * 8 + c] = min(s_red[t * 8 + c], s_red[(t + off) * 8 + c]);
        #pragma unroll
        for (int c = 4; c < 8; ++c)
          s_red[t * 8 + c] = max(s_red[t * 8 + c], s_red[(t + off) * 8 + c]);
      }
      __syncthreads();
    }
    if (t == 0) {
      const float vs[4] = {1.0f, 0.4f, 0.4f, 0.4f};
      #pragma unroll
      for (int c = 0; c < 4; ++c) {
        float mnv = fkey_unmap(s_red[c]);
        float mxv = fkey_unmap(s_red[4 + c]);
        float pmin = mnv - vs[c] * 2.0f;
        float pmax = mxv + vs[c] * 2.0f;
        hdr->pc_min[c] = pmin;
        hdr->dims[c] = (int)rintf((pmax - pmin) / vs[c]) + 3;  // half-even
      }
    }
  }
  grid.sync();

  const float pc0 = hdr->pc_min[0], pc1 = hdr->pc_min[1];
  const float pc2 = hdr->pc_min[2], pc3 = hdr->pc_min[3];
  const int d1 = hdr->dims[1], d2 = hdr->dims[2], d3 = hdr->dims[3];

  // ---- phase 2: mark bitmap ----
  if (gtid < n) {
    float4 p = pts[gtid];
    int c[4]; coors_from(p, pc0, pc1, pc2, pc3, c);
    int key = ((c[0] * d1 + c[1]) * d2 + c[2]) * d3 + c[3];
    unsigned uk = (unsigned)key;
    if (uk < WMAX * 32u) atomicOr(&bm[uk >> 5], 1u << (uk & 31u));
  }
  grid.sync();

  // ---- phase 3: scanA over virtual superblocks ----
  for (int vb = blockIdx.x; vb < PBLK; vb += gridDim.x) {
    size_t base = (size_t)vb * 2048 + (size_t)t * 8;
    uint4 a = *(const uint4*)(bm + base);
    uint4 b4 = *(const uint4*)(bm + base + 4);
    unsigned pc[8] = {(unsigned)__popc(a.x), (unsigned)__popc(a.y),
                      (unsigned)__popc(a.z), (unsigned)__popc(a.w),
                      (unsigned)__popc(b4.x), (unsigned)__popc(b4.y),
                      (unsigned)__popc(b4.z), (unsigned)__popc(b4.w)};
    unsigned sum = 0;
    #pragma unroll
    for (int k = 0; k < 8; ++k) sum += pc[k];
    s_scan[t] = sum; __syncthreads();
    for (int off = 1; off < 256; off <<= 1) {
      unsigned v = (t >= off) ? s_scan[t - off] : 0u;
      __syncthreads();
      s_scan[t] += v;
      __syncthreads();
    }
    unsigned run = s_scan[t] - sum;
    unsigned r[8];
    #pragma unroll
    for (int k = 0; k < 8; ++k) { r[k] = run; run += pc[k]; }
    uint4 o;
    o.x = (r[0] & 0xFFFFu) | (r[1] << 16);
    o.y = (r[2] & 0xFFFFu) | (r[3] << 16);
    o.z = (r[4] & 0xFFFFu) | (r[5] << 16);
    o.w = (r[6] & 0xFFFFu) | (r[7] << 16);
    *(uint4*)(rank16 + base) = o;
    if (t == 255) part[vb] = s_scan[255];
    __syncthreads();
  }
  grid.sync();

  // ---- phase 4: scanB (block 0 only) ----
  if (blockIdx.x == 0) {
    int lo = t * CHUNK;
    unsigned local[CHUNK];
    unsigned sum = 0;
    #pragma unroll
    for (int k = 0; k < CHUNK; ++k) {
      int j = lo + k;
      local[k] = (j < PBLK) ? part[j] : 0u;
      sum += local[k];
    }
    s_scan[t] = sum; __syncthreads();
    for (int off = 1; off < 256; off <<= 1) {
      unsigned v = (t >= off) ? s_scan[t - off] : 0u;
      __syncthreads();
      s_scan[t] += v;
      __syncthreads();
    }
    unsigned run = s_scan[t] - sum;
    #pragma unroll
    for (int k = 0; k < CHUNK; ++k) {
      int j = lo + k;
      if (j < PBLK) part[j] = run;
      run += local[k];
    }
    if (t == 255) hdr->M = (int)s_scan[255];
  }
  grid.sync();

  // ---- phase 5: probe (hit list + count atomics) ----
  if (t == 0) s_cnt = 0;
  __syncthreads();
  {
    const float gg = 0.4f * 0.4f;
    const float decay2 = (gg + gg + gg) * 0.25f;   // bitwise == ref
    if (gtid < n) {
      float4 p = pts[gtid];
      int c[4]; coors_from(p, pc0, pc1, pc2, pc3, c);
      #pragma unroll
      for (int dx = -1; dx <= 1; ++dx) {
        #pragma unroll
        for (int dy = -1; dy <= 1; ++dy) {
          int n1 = c[1] + dx, n2 = c[2] + dy;
          int kc = ((c[0] * d1 + n1) * d2 + n2) * d3 + c[3];  // dz = 0
          unsigned k = (unsigned)kc;
          if (k < 1u || k + 1u >= WMAX * 32u) continue;       // safety
          unsigned w = k >> 5, b = k & 31u;
          unsigned cur = bm[w];
          unsigned tri;
          if (b == 0u)
            tri = (bm[w - 1] >> 31) | ((cur & 3u) << 1);
          else if (b == 31u)
            tri = ((cur >> 30) & 3u) | ((bm[w + 1] & 1u) << 2);
          else
            tri = (cur >> (b - 1)) & 7u;
          if (!tri) continue;
          #pragma unroll
          for (int j = 0; j < 3; ++j) {
            if (!((tri >> j) & 1u)) continue;
            unsigned kj = k + (unsigned)(j - 1);
            unsigned wj = kj >> 5, bj = kj & 31u;
            unsigned word = (wj == w) ? cur : bm[wj];
            int r = (int)(part[kj >> 16] + (unsigned)rank16[wj] +
                          __popc(word & ((1u << bj) - 1u)));
            int n3 = c[3] + (j - 1);
            float cx = (float)(n1 - 1) * 0.4f + pc1;
            float cy = (float)(n2 - 1) * 0.4f + pc2;
            float cz = (float)(n3 - 1) * 0.4f + pc3;
            float ex = p.y - cx, ey = p.z - cy, ez = p.w - cz;
            float dd = ex * ex + ey * ey + ez * ez;
            float wgt = expf(-dd / decay2);
            int pos = atomicAdd(&s_cnt, 1);
            if (pos < HCAP) {
              s_hi[pos] = gtid; s_hr[pos] = r; s_hw[pos] = wgt;
            } else {
              direct_accum(acc, r, wgt, p);      // LDS overflow (rare)
            }
          }
        }
      }
    }
    __syncthreads();
    int cnt = min(s_cnt, HCAP);
    if (t == 0) s_base = (int)atomicAdd(g_cnt, (unsigned)cnt);
    __syncthreads();
    int base = s_base;
    for (int j = t; j < cnt; j += 256) {
      int gpos = base + j;
      int r = s_hr[j];
      if (gpos < HITCAP) {
        hit_i[gpos] = s_hi[j];
        hit_r[gpos] = r;
        hit_w[gpos] = s_hw[j];
        atomicAdd((unsigned*)(acc + (size_t)r * 12 + 11), 1u);
      } else {
        direct_accum(acc, r, s_hw[j], pts[s_hi[j]]);  // overflow (rare)
      }
    }
  }
  grid.sync();

  // ---- phase 6: drain ----
  {
    int total = min((int)*g_cnt, HITCAP);
    for (int j = gtid; j < total; j += gridT) {
      int r = hit_r[j];
      float wgt = hit_w[j];
      float4 q = pts[hit_i[j]];
      float* a = acc + (size_t)r * 12;
      unsigned cctr = *(const unsigned*)(a + 11);
      if (cctr == 1u) {
        float4 v0 = {wgt, wgt * q.x, wgt * q.y, wgt * q.z};
        float4 v1 = {wgt * q.w, wgt * q.y * q.y, wgt * q.y * q.z,
                     wgt * q.y * q.w};
        float4 v2 = {wgt * q.z * q.z, wgt * q.z * q.w, wgt * q.w * q.w, 0.0f};
        float4* av = (float4*)a;
        av[0] = v0; av[1] = v1; av[2] = v2;
      } else {
        atomicAdd(a + 0, wgt);
        atomicAdd(a + 1, wgt * q.x);
        atomicAdd(a + 2, wgt * q.y);
        atomicAdd(a + 3, wgt * q.z);
        atomicAdd(a + 4, wgt * q.w);
        atomicAdd(a + 5, wgt * q.y * q.y);
        atomicAdd(a + 6, wgt * q.y * q.z);
        atomicAdd(a + 7, wgt * q.y * q.w);
        atomicAdd(a + 8, wgt * q.z * q.z);
        atomicAdd(a + 9, wgt * q.z * q.w);
        atomicAdd(a + 10, wgt * q.w * q.w);
      }
    }
  }
  grid.sync();

  // ---- phase 7: finalize ----
  if (gtid < n) {
    const float4* av = (const float4*)(acc + (size_t)gtid * 12);
    float4 v0 = av[0], v1 = av[1], v2 = av[2];
    float ws = v0.x;
    bool ok = (gtid < hdr->M) && (ws > 0.0f);
    jacobi_out(ws, v0, v1, v2, ok, out_mu + (size_t)gtid * 4,
               out_R + (size_t)gtid * 9);
  }
}

// ===================== fallback multi-kernel path (R4) ======================
__global__ void k_minmax(const float4* __restrict__ pts, int n,
                         unsigned* __restrict__ mmpart) {
  __shared__ unsigned smem[4 * 8];
  float mn[4] = { INFINITY,  INFINITY,  INFINITY,  INFINITY};
  float mx[4] = {-INFINITY, -INFINITY, -INFINITY, -INFINITY};
  for (int i = blockIdx.x * blockDim.x + threadIdx.x; i < n;
       i += gridDim.x * blockDim.x) {
    float4 p = pts[i];
    mn[0] = fminf(mn[0], p.x); mx[0] = fmaxf(mx[0], p.x);
    mn[1] = fminf(mn[1], p.y); mx[1] = fmaxf(mx[1], p.y);
    mn[2] = fminf(mn[2], p.z); mx[2] = fmaxf(mx[2], p.z);
    mn[3] = fminf(mn[3], p.w); mx[3] = fmaxf(mx[3], p.w);
  }
  #pragma unroll
  for (int off = 32; off > 0; off >>= 1) {
    #pragma unroll
    for (int c = 0; c < 4; ++c) {
      mn[c] = fminf(mn[c], __shfl_down(mn[c], off));
      mx[c] = fmaxf(mx[c], __shfl_down(mx[c], off));
    }
  }
  int wave = threadIdx.x >> 6;
  if ((threadIdx.x & 63) == 0) {
    #pragma unroll
    for (int c = 0; c < 4; ++c) {
      smem[wave * 8 + c]     = fkey_map(mn[c]);
      smem[wave * 8 + 4 + c] = fkey_map(mx[c]);
    }
  }
  __syncthreads();
  int t = threadIdx.x;
  if (t < 8) {
    unsigned u = smem[t];
    #pragma unroll
    for (int w = 1; w < 4; ++w)
      u = (t < 4) ? min(u, smem[w * 8 + t]) : max(u, smem[w * 8 + t]);
    mmpart[blockIdx.x * 8 + t] = u;
  }
}

__global__ void k_prep(const unsigned* __restrict__ mmpart, Hdr* h, int nb) {
  __shared__ unsigned s[256 * 8];
  int t = threadIdx.x;
  unsigned v[8];
  #pragma unroll
  for (int c = 0; c < 4; ++c) { v[c] = 0xFFFFFFFFu; v[4 + c] = 0u; }
  for (int b = t; b < nb; b += 256) {
    #pragma unroll
    for (int c = 0; c < 4; ++c) {
      v[c] = min(v[c], mmpart[b * 8 + c]);
      v[4 + c] = max(v[4 + c], mmpart[b * 8 + 4 + c]);
    }
  }
  #pragma unroll
  for (int c = 0; c < 8; ++c) s[t * 8 + c] = v[c];
  __syncthreads();
  for (int off = 128; off > 0; off >>= 1) {
    if (t < off) {
      #pragma unroll
      for (int c = 0; c < 4; ++c)
        s[t * 8 + c] = min(s[t * 8 + c], s[(t + off) * 8 + c]);
      #pragma unroll
      for (int c = 4; c < 8; ++c)
        s[t * 8 + c] = max(s[t * 8 + c], s[(t + off) * 8 + c]);
    }
    __syncthreads();
  }
  if (t == 0) {
    const float vs[4] = {1.0f, 0.4f, 0.4f, 0.4f};
    #pragma unroll
    for (int c = 0; c < 4; ++c) {
      float mn = fkey_unmap(s[c]);
      float mx = fkey_unmap(s[4 + c]);
      float pmin = mn - vs[c] * 2.0f;
      float pmax = mx + vs[c] * 2.0f;
      h->pc_min[c] = pmin;
      h->dims[c] = (int)rintf((pmax - pmin) / vs[c]) + 3;
    }
  }
}

__global__ void k_mark(const float4* __restrict__ pts, int n,
                       const Hdr* __restrict__ h, unsigned* __restrict__ bm) {
  int i = blockIdx.x * 256 + threadIdx.x;
  if (i >= n) return;
  float4 p = pts[i];
  int c[4];
  coors_from(p, h->pc_min[0], h->pc_min[1], h->pc_min[2], h->pc_min[3], c);
  int key = ((c[0] * h->dims[1] + c[1]) * h->dims[2] + c[2]) * h->dims[3] + c[3];
  unsigned uk = (unsigned)key;
  if (uk >= WMAX * 32u) return;
  atomicOr(&bm[uk >> 5], 1u << (uk & 31u));
}

__global__ void k_scanA(const unsigned* __restrict__ bm,
                        unsigned short* __restrict__ rank16,
                        unsigned* __restrict__ part) {
  __shared__ unsigned s[256];
  int t = threadIdx.x;
  size_t base = (size_t)blockIdx.x * 2048 + (size_t)t * 8;
  uint4 a = *(const uint4*)(bm + base);
  uint4 b = *(const uint4*)(bm + base + 4);
  unsigned pc[8] = {(unsigned)__popc(a.x), (unsigned)__popc(a.y),
                    (unsigned)__popc(a.z), (unsigned)__popc(a.w),
                    (unsigned)__popc(b.x), (unsigned)__popc(b.y),
                    (unsigned)__popc(b.z), (unsigned)__popc(b.w)};
  unsigned sum = 0;
  #pragma unroll
  for (int k = 0; k < 8; ++k) sum += pc[k];
  s[t] = sum; __syncthreads();
  for (int off = 1; off < 256; off <<= 1) {
    unsigned v = (t >= off) ? s[t - off] : 0u;
    __syncthreads();
    s[t] += v;
    __syncthreads();
  }
  unsigned run = s[t] - sum;
  unsigned r[8];
  #pragma unroll
  for (int k = 0; k < 8; ++k) { r[k] = run; run += pc[k]; }
  uint4 o;
  o.x = (r[0] & 0xFFFFu) | (r[1] << 16);
  o.y = (r[2] & 0xFFFFu) | (r[3] << 16);
  o.z = (r[4] & 0xFFFFu) | (r[5] << 16);
  o.w = (r[6] & 0xFFFFu) | (r[7] << 16);
  *(uint4*)(rank16 + base) = o;
  if (t == 255) part[blockIdx.x] = s[255];
}

__global__ void k_scanB(unsigned* __restrict__ part, Hdr* h) {
  __shared__ unsigned s[256];
  int t = threadIdx.x;
  int lo = t * CHUNK;
  unsigned local[CHUNK];
  unsigned sum = 0;
  #pragma unroll
  for (int k = 0; k < CHUNK; ++k) {
    int j = lo + k;
    local[k] = (j < PBLK) ? part[j] : 0u;
    sum += local[k];
  }
  s[t] = sum; __syncthreads();
  for (int off = 1; off < 256; off <<= 1) {
    unsigned v = (t >= off) ? s[t - off] : 0u;
    __syncthreads();
    s[t] += v;
    __syncthreads();
  }
  unsigned run = s[t] - sum;
  #pragma unroll
  for (int k = 0; k < CHUNK; ++k) {
    int j = lo + k;
    if (j < PBLK) part[j] = run;
    run += local[k];
  }
  if (t == 255) h->M = (int)s[255];
}

__global__ void k_probe(const float4* __restrict__ pts, int n,
                        const Hdr* __restrict__ h,
                        const unsigned* __restrict__ bm,
                        const unsigned short* __restrict__ rank16,
                        const unsigned* __restrict__ part,
                        int* __restrict__ hit_i, int* __restrict__ hit_r,
                        float* __restrict__ hit_w,
                        unsigned* __restrict__ g_cnt,
                        float* __restrict__ acc) {
  __shared__ int s_cnt;
  __shared__ int s_base;
  __shared__ int   s_i[HCAP];
  __shared__ int   s_r[HCAP];
  __shared__ float s_w[HCAP];
  if (threadIdx.x == 0) s_cnt = 0;
  __syncthreads();
  int i = blockIdx.x * 256 + threadIdx.x;
  const float gg = 0.4f * 0.4f;
  const float decay2 = (gg + gg + gg) * 0.25f;
  if (i < n) {
    float4 p = pts[i];
    int c[4];
    coors_from(p, h->pc_min[0], h->pc_min[1], h->pc_min[2], h->pc_min[3], c);
    int d1 = h->dims[1], d2 = h->dims[2], d3 = h->dims[3];
    float m1 = h->pc_min[1], m2 = h->pc_min[2], m3 = h->pc_min[3];
    #pragma unroll
    for (int dx = -1; dx <= 1; ++dx) {
      #pragma unroll
      for (int dy = -1; dy <= 1; ++dy) {
        int n1 = c[1] + dx, n2 = c[2] + dy;
        int kc = ((c[0] * d1 + n1) * d2 + n2) * d3 + c[3];
        unsigned k = (unsigned)kc;
        if (k < 1u || k + 1u >= WMAX * 32u) continue;
        unsigned w = k >> 5, b = k & 31u;
        unsigned cur = bm[w];
        unsigned tri;
        if (b == 0u)
          tri = (bm[w - 1] >> 31) | ((cur & 3u) << 1);
        else if (b == 31u)
          tri = ((cur >> 30) & 3u) | ((bm[w + 1] & 1u) << 2);
        else
          tri = (cur >> (b - 1)) & 7u;
        if (!tri) continue;
        #pragma unroll
        for (int j = 0; j < 3; ++j) {
          if (!((tri >> j) & 1u)) continue;
          unsigned kj = k + (unsigned)(j - 1);
          unsigned wj = kj >> 5, bj = kj & 31u;
          unsigned word = (wj == w) ? cur : bm[wj];
          int r = (int)(part[kj >> 16] + (unsigned)rank16[wj] +
                        __popc(word & ((1u << bj) - 1u)));
          int n3 = c[3] + (j - 1);
          float cx = (float)(n1 - 1) * 0.4f + m1;
          float cy = (float)(n2 - 1) * 0.4f + m2;
          float cz = (float)(n3 - 1) * 0.4f + m3;
          float ex = p.y - cx, ey = p.z - cy, ez = p.w - cz;
          float dd = ex * ex + ey * ey + ez * ez;
          float wgt = expf(-dd / decay2);
          int pos = atomicAdd(&s_cnt, 1);
          if (pos < HCAP) {
            s_i[pos] = i; s_r[pos] = r; s_w[pos] = wgt;
          } else {
            direct_accum(acc, r, wgt, p);
          }
        }
      }
    }
  }
  __syncthreads();
  int cnt = min(s_cnt, HCAP);
  if (threadIdx.x == 0) s_base = (int)atomicAdd(g_cnt, (unsigned)cnt);
  __syncthreads();
  int base = s_base;
  for (int j = threadIdx.x; j < cnt; j += 256) {
    int gpos = base + j;
    int r = s_r[j];
    if (gpos < HITCAP) {
      hit_i[gpos] = s_i[j];
      hit_r[gpos] = r;
      hit_w[gpos] = s_w[j];
      atomicAdd((unsigned*)(acc + (size_t)r * 12 + 11), 1u);
    } else {
      direct_accum(acc, r, s_w[j], pts[s_i[j]]);
    }
  }
}

__global__ void k_drain(const float4* __restrict__ pts,
                        const int* __restrict__ hit_i,
                        const int* __restrict__ hit_r,
                        const float* __restrict__ hit_w,
                        const unsigned* __restrict__ g_cnt,
                        float* __restrict__ acc) {
  int total = min((int)*g_cnt, HITCAP);
  for (int j = blockIdx.x * 256 + threadIdx.x; j < total;
       j += gridDim.x * 256) {
    int r = hit_r[j];
    float wgt = hit_w[j];
    float4 q = pts[hit_i[j]];
    float* a = acc + (size_t)r * 12;
    unsigned c = *(const unsigned*)(a + 11);
    if (c == 1u) {
      float4 v0 = {wgt, wgt * q.x, wgt * q.y, wgt * q.z};
      float4 v1 = {wgt * q.w, wgt * q.y * q.y, wgt * q.y * q.z,
                   wgt * q.y * q.w};
      float4 v2 = {wgt * q.z * q.z, wgt * q.z * q.w, wgt * q.w * q.w, 0.0f};
      float4* av = (float4*)a;
      av[0] = v0; av[1] = v1; av[2] = v2;
    } else {
      atomicAdd(a + 0, wgt);
      atomicAdd(a + 1, wgt * q.x);
      atomicAdd(a + 2, wgt * q.y);
      atomicAdd(a + 3, wgt * q.z);
      atomicAdd(a + 4, wgt * q.w);
      atomicAdd(a + 5, wgt * q.y * q.y);
      atomicAdd(a + 6, wgt * q.y * q.z);
      atomicAdd(a + 7, wgt * q.y * q.w);
      atomicAdd(a + 8, wgt * q.z * q.z);
      atomicAdd(a + 9, wgt * q.z * q.w);
      atomicAdd(a + 10, wgt * q.w * q.w);
    }
  }
}

__global__ void k_finalize(const Hdr* __restrict__ h,
                           const float* __restrict__ acc,
                           float* __restrict__ out_mu,
                           float* __restrict__ out_R, int n) {
  int i = blockIdx.x * 256 + threadIdx.x;
  if (i >= n) return;
  const float4* av = (const float4*)(acc + (size_t)i * 12);
  float4 v0 = av[0], v1 = av[1], v2 = av[2];
  float ws = v0.x;
  bool ok = (i < h->M) && (ws > 0.0f);
  jacobi_out(ws, v0, v1, v2, ok, out_mu + (size_t)i * 4,
             out_R + (size_t)i * 9);
}

// ============================================================================
extern "C" void kernel_launch(void* const* d_in, const int* in_sizes, int n_in,
                              void* d_out, int out_size, void* d_ws,
                              size_t ws_size, hipStream_t stream) {
  const float4* pts = (const float4*)d_in[0];
  int n = in_sizes[0] / 4;
  float* out = (float*)d_out;
  float* outR = out + (size_t)4 * n;

  char* ws = (char*)d_ws;
  Hdr* hdr = (Hdr*)ws;
  size_t off = 256;
  unsigned* mmpart = (unsigned*)(ws + off);      off += 2048 * 8 * 4;
  unsigned* bm = (unsigned*)(ws + off);          off += (size_t)WMAX * 4;
  unsigned short* rank16 = (unsigned short*)(ws + off); off += (size_t)WMAX * 2;
  unsigned* part = (unsigned*)(ws + off);        off += 4096 * 4;
  unsigned* g_cnt = (unsigned*)(ws + off);       off += 256;
  int* hit_i = (int*)(ws + off);                 off += (size_t)HITCAP * 4;
  int* hit_r = (int*)(ws + off);                 off += (size_t)HITCAP * 4;
  float* hit_w = (float*)(ws + off);             off += (size_t)HITCAP * 4;
  float* acc = (float*)(ws + off);               // n * 12 floats
  size_t needed = off + (size_t)n * 12 * 4;
  if (ws_size < needed) return;

  int nb = (n + 255) / 256;   // 782 blocks <= coop capacity (4/CU * 256)

  void* args[] = {(void*)&pts, (void*)&n, (void*)&hdr, (void*)&mmpart,
                  (void*)&bm, (void*)&rank16, (void*)&part, (void*)&g_cnt,
                  (void*)&hit_i, (void*)&hit_r, (void*)&hit_w, (void*)&acc,
                  (void*)&out, (void*)&outR};
  hipError_t err = hipLaunchCooperativeKernel((void*)k_fused, dim3(nb),
                                              dim3(256), args, 0, stream);
  if (err == hipSuccess) return;

  // -------- fallback: R4 multi-kernel pipeline --------
  hipMemsetAsync(bm, 0, (size_t)WMAX * 4, stream);
  hipMemsetAsync(g_cnt, 0, 256, stream);
  hipMemsetAsync(acc, 0, (size_t)n * 12 * 4, stream);
  k_minmax<<<256, 256, 0, stream>>>(pts, n, mmpart);
  k_prep<<<1, 256, 0, stream>>>(mmpart, hdr, 256);
  k_mark<<<nb, 256, 0, stream>>>(pts, n, hdr, bm);
  k_scanA<<<PBLK, 256, 0, stream>>>(bm, rank16, part);
  k_scanB<<<1, 256, 0, stream>>>(part, hdr);
  k_probe<<<nb, 256, 0, stream>>>(pts, n, hdr, bm, rank16, part,
                                  hit_i, hit_r, hit_w, g_cnt, acc);
  k_drain<<<512, 256, 0, stream>>>(pts, hit_i, hit_r, hit_w, g_cnt, acc);
  k_finalize<<<nb, 256, 0, stream>>>(hdr, acc, out, outR, n);
}

// Round 6
// 176.817 us; speedup vs baseline: 4.4779x; 4.4779x over previous
//
#include <hip/hip_runtime.h>
#include <stdint.h>

// ---------------------------------------------------------------------------
// PrimitiveFitting: voxel-hash primitive fitting (mu + scaled-eigvec R).
//
// R5 post-mortem: cooperative grid.sync costs ~85us/barrier on 8 XCDs
// (atomic spin at coherence fabric) -> 7 syncs = +600us. REVERTED to the
// multi-kernel R4 pipeline; kernel-boundary barriers are ~3us each.
// R6 changes vs R4: memsets folded into k_zero_minmax (11 -> 8 dispatches),
// 784-block zero+minmax for full write BW.
// ---------------------------------------------------------------------------

#define WMAX   5402624u       // bitmap words = 2638 * 2048  (>= 10*258^3 / 32)
#define PBLK   2638           // scan superblocks (2048 words = 65536 bits)
#define CHUNK  11             // ceil(PBLK / 256)
#define HCAP   1024           // LDS staging entries / block (expected ~280)
#define HITCAP 786432         // global hit list capacity (expected ~216k)
#define MMB    784            // zero+minmax blocks

struct Hdr {
  float pc_min[4];
  int   dims[4];
  int   M;
};

__device__ __forceinline__ unsigned fkey_map(float f) {
  unsigned u = __float_as_uint(f);
  return (u & 0x80000000u) ? ~u : (u | 0x80000000u);
}
__device__ __forceinline__ float fkey_unmap(unsigned u) {
  unsigned b = (u & 0x80000000u) ? (u ^ 0x80000000u) : ~u;
  return __uint_as_float(b);
}

__device__ __forceinline__ void coors_from(float4 p, float pc0, float pc1,
                                           float pc2, float pc3, int c[4]) {
  // Must match numpy bitwise: f32 subtract, IEEE f32 divide, rint (half-even).
  c[0] = (int)rintf((p.x - pc0) / 1.0f) + 1;
  c[1] = (int)rintf((p.y - pc1) / 0.4f) + 1;
  c[2] = (int)rintf((p.z - pc2) / 0.4f) + 1;
  c[3] = (int)rintf((p.w - pc3) / 0.4f) + 1;
}

__device__ __forceinline__ void direct_accum(float* __restrict__ acc, int r,
                                             float wgt, float4 p) {
  float* a = acc + (size_t)r * 12;
  atomicAdd((unsigned*)(a + 11), 1u);
  atomicAdd(a + 0, wgt);
  atomicAdd(a + 1, wgt * p.x);
  atomicAdd(a + 2, wgt * p.y);
  atomicAdd(a + 3, wgt * p.z);
  atomicAdd(a + 4, wgt * p.w);
  atomicAdd(a + 5, wgt * p.y * p.y);
  atomicAdd(a + 6, wgt * p.y * p.z);
  atomicAdd(a + 7, wgt * p.y * p.w);
  atomicAdd(a + 8, wgt * p.z * p.z);
  atomicAdd(a + 9, wgt * p.z * p.w);
  atomicAdd(a + 10, wgt * p.w * p.w);
}

__device__ __forceinline__ void jacobi_out(float ws, float4 v0, float4 v1,
                                           float4 v2, bool ok,
                                           float* mu_o, float* R_o) {
  if (!ok) {
    mu_o[0] = mu_o[1] = mu_o[2] = mu_o[3] = 0.0f;
    #pragma unroll
    for (int k = 0; k < 9; ++k) R_o[k] = 0.0f;
    return;
  }
  float mu0 = v0.y / ws, mu1 = v0.z / ws, mu2 = v0.w / ws, mu3 = v1.x / ws;
  float A[3][3];
  A[0][0] = v1.y / ws - mu1 * mu1;
  A[0][1] = A[1][0] = v1.z / ws - mu1 * mu2;
  A[0][2] = A[2][0] = v1.w / ws - mu1 * mu3;
  A[1][1] = v2.x / ws - mu2 * mu2;
  A[1][2] = A[2][1] = v2.y / ws - mu2 * mu3;
  A[2][2] = v2.z / ws - mu3 * mu3;

  float V[3][3] = {{1.f, 0.f, 0.f}, {0.f, 1.f, 0.f}, {0.f, 0.f, 1.f}};
  for (int sweep = 0; sweep < 8; ++sweep) {
    #pragma unroll
    for (int pi = 0; pi < 3; ++pi) {
      int p = (pi == 2) ? 1 : 0;
      int q = (pi == 0) ? 1 : 2;
      float apq = A[p][q];
      if (apq == 0.0f) continue;
      float app = A[p][p], aqq = A[q][q];
      float theta = (aqq - app) / (2.0f * apq);
      float t = 1.0f / (fabsf(theta) + sqrtf(theta * theta + 1.0f));
      if (theta < 0.0f) t = -t;
      float cth = 1.0f / sqrtf(t * t + 1.0f);
      float sth = t * cth;
      A[p][p] = app - t * apq;
      A[q][q] = aqq + t * apq;
      A[p][q] = A[q][p] = 0.0f;
      int k = 3 - p - q;
      float akp = A[k][p], akq = A[k][q];
      A[k][p] = A[p][k] = cth * akp - sth * akq;
      A[k][q] = A[q][k] = sth * akp + cth * akq;
      #pragma unroll
      for (int r = 0; r < 3; ++r) {
        float vp = V[r][p], vq = V[r][q];
        V[r][p] = cth * vp - sth * vq;
        V[r][q] = sth * vp + cth * vq;
      }
    }
  }
  float a[3] = {fabsf(A[0][0]), fabsf(A[1][1]), fabsf(A[2][2])};
  int idx[3] = {0, 1, 2};
  if (a[idx[0]] < a[idx[1]]) { int t = idx[0]; idx[0] = idx[1]; idx[1] = t; }
  if (a[idx[1]] < a[idx[2]]) { int t = idx[1]; idx[1] = idx[2]; idx[2] = t; }
  if (a[idx[0]] < a[idx[1]]) { int t = idx[0]; idx[0] = idx[1]; idx[1] = t; }
  float S0 = fmaxf(sqrtf(a[idx[0]]), 1e-6f);
  float S1 = fmaxf(sqrtf(a[idx[1]]), 1e-6f);
  float S2 = fmaxf(sqrtf(a[idx[2]]), 1e-6f);
  float U[3][3];
  #pragma unroll
  for (int r = 0; r < 3; ++r) {
    U[r][0] = V[r][idx[0]];
    U[r][1] = V[r][idx[1]];
    U[r][2] = V[r][idx[2]];
  }
  float det = U[0][0] * (U[1][1] * U[2][2] - U[1][2] * U[2][1])
            - U[0][1] * (U[1][0] * U[2][2] - U[1][2] * U[2][0])
            + U[0][2] * (U[1][0] * U[2][1] - U[1][1] * U[2][0]);
  float f2 = (det < 0.0f) ? -1.0f : 1.0f;
  mu_o[0] = mu0; mu_o[1] = mu1; mu_o[2] = mu2; mu_o[3] = mu3;
  R_o[0] = U[0][0] * S0; R_o[1] = U[0][1] * S1; R_o[2] = U[0][2] * S2 * f2;
  R_o[3] = U[1][0] * S0; R_o[4] = U[1][1] * S1; R_o[5] = U[1][2] * S2 * f2;
  R_o[6] = U[2][0] * S0; R_o[7] = U[2][1] * S1; R_o[8] = U[2][2] * S2 * f2;
}

// zero bm/acc/g_cnt + per-block minmax partials (folded: saves 3 dispatches)
__global__ void k_zero_minmax(const float4* __restrict__ pts, int n,
                              unsigned* __restrict__ mmpart,
                              unsigned* __restrict__ bm,
                              float* __restrict__ acc,
                              unsigned* __restrict__ g_cnt) {
  __shared__ unsigned smem[4 * 8];
  const int gtid = blockIdx.x * 256 + threadIdx.x;
  const int gridT = gridDim.x * 256;

  uint4 z = {0u, 0u, 0u, 0u};
  uint4* bm4 = (uint4*)bm;
  for (int i = gtid; i < (int)(WMAX / 4); i += gridT) bm4[i] = z;
  uint4* acc4 = (uint4*)acc;
  int acc4n = n * 3;                          // n*12 floats / 4
  for (int i = gtid; i < acc4n; i += gridT) acc4[i] = z;
  if (gtid == 0) *g_cnt = 0u;

  float mn[4] = { INFINITY,  INFINITY,  INFINITY,  INFINITY};
  float mx[4] = {-INFINITY, -INFINITY, -INFINITY, -INFINITY};
  for (int i = gtid; i < n; i += gridT) {
    float4 p = pts[i];
    mn[0] = fminf(mn[0], p.x); mx[0] = fmaxf(mx[0], p.x);
    mn[1] = fminf(mn[1], p.y); mx[1] = fmaxf(mx[1], p.y);
    mn[2] = fminf(mn[2], p.z); mx[2] = fmaxf(mx[2], p.z);
    mn[3] = fminf(mn[3], p.w); mx[3] = fmaxf(mx[3], p.w);
  }
  #pragma unroll
  for (int off = 32; off > 0; off >>= 1) {
    #pragma unroll
    for (int c = 0; c < 4; ++c) {
      mn[c] = fminf(mn[c], __shfl_down(mn[c], off));
      mx[c] = fmaxf(mx[c], __shfl_down(mx[c], off));
    }
  }
  int wave = threadIdx.x >> 6;
  if ((threadIdx.x & 63) == 0) {
    #pragma unroll
    for (int c = 0; c < 4; ++c) {
      smem[wave * 8 + c]     = fkey_map(mn[c]);
      smem[wave * 8 + 4 + c] = fkey_map(mx[c]);
    }
  }
  __syncthreads();
  int t = threadIdx.x;
  if (t < 8) {
    unsigned u = smem[t];
    #pragma unroll
    for (int w = 1; w < 4; ++w)
      u = (t < 4) ? min(u, smem[w * 8 + t]) : max(u, smem[w * 8 + t]);
    mmpart[blockIdx.x * 8 + t] = u;
  }
}

__global__ void k_prep(const unsigned* __restrict__ mmpart, Hdr* h, int nb) {
  __shared__ unsigned s[256 * 8];
  int t = threadIdx.x;
  unsigned v[8];
  #pragma unroll
  for (int c = 0; c < 4; ++c) { v[c] = 0xFFFFFFFFu; v[4 + c] = 0u; }
  for (int b = t; b < nb; b += 256) {
    #pragma unroll
    for (int c = 0; c < 4; ++c) {
      v[c] = min(v[c], mmpart[b * 8 + c]);
      v[4 + c] = max(v[4 + c], mmpart[b * 8 + 4 + c]);
    }
  }
  #pragma unroll
  for (int c = 0; c < 8; ++c) s[t * 8 + c] = v[c];
  __syncthreads();
  for (int off = 128; off > 0; off >>= 1) {
    if (t < off) {
      #pragma unroll
      for (int c = 0; c < 4; ++c)
        s[t * 8 + c] = min(s[t * 8 + c], s[(t + off) * 8 + c]);
      #pragma unroll
      for (int c = 4; c < 8; ++c)
        s[t * 8 + c] = max(s[t * 8 + c], s[(t + off) * 8 + c]);
    }
    __syncthreads();
  }
  if (t == 0) {
    const float vs[4] = {1.0f, 0.4f, 0.4f, 0.4f};
    #pragma unroll
    for (int c = 0; c < 4; ++c) {
      float mn = fkey_unmap(s[c]);
      float mx = fkey_unmap(s[4 + c]);
      float pmin = mn - vs[c] * 2.0f;
      float pmax = mx + vs[c] * 2.0f;
      h->pc_min[c] = pmin;
      h->dims[c] = (int)rintf((pmax - pmin) / vs[c]) + 3;  // np.round half-even
    }
  }
}

__global__ void k_mark(const float4* __restrict__ pts, int n,
                       const Hdr* __restrict__ h, unsigned* __restrict__ bm) {
  int i = blockIdx.x * 256 + threadIdx.x;
  if (i >= n) return;
  float4 p = pts[i];
  int c[4];
  coors_from(p, h->pc_min[0], h->pc_min[1], h->pc_min[2], h->pc_min[3], c);
  int key = ((c[0] * h->dims[1] + c[1]) * h->dims[2] + c[2]) * h->dims[3] + c[3];
  unsigned uk = (unsigned)key;
  if (uk >= WMAX * 32u) return;   // safety (never taken for valid data)
  atomicOr(&bm[uk >> 5], 1u << (uk & 31u));
}

// 2048 words / block: per-thread 8-word popcount prefix + one LDS scan.
__global__ void k_scanA(const unsigned* __restrict__ bm,
                        unsigned short* __restrict__ rank16,
                        unsigned* __restrict__ part) {
  __shared__ unsigned s[256];
  int t = threadIdx.x;
  size_t base = (size_t)blockIdx.x * 2048 + (size_t)t * 8;
  uint4 a = *(const uint4*)(bm + base);
  uint4 b = *(const uint4*)(bm + base + 4);
  unsigned pc[8] = {(unsigned)__popc(a.x), (unsigned)__popc(a.y),
                    (unsigned)__popc(a.z), (unsigned)__popc(a.w),
                    (unsigned)__popc(b.x), (unsigned)__popc(b.y),
                    (unsigned)__popc(b.z), (unsigned)__popc(b.w)};
  unsigned sum = 0;
  #pragma unroll
  for (int k = 0; k < 8; ++k) sum += pc[k];
  s[t] = sum; __syncthreads();
  for (int off = 1; off < 256; off <<= 1) {
    unsigned v = (t >= off) ? s[t - off] : 0u;
    __syncthreads();
    s[t] += v;
    __syncthreads();
  }
  unsigned run = s[t] - sum;
  unsigned r[8];
  #pragma unroll
  for (int k = 0; k < 8; ++k) { r[k] = run; run += pc[k]; }
  uint4 o;
  o.x = (r[0] & 0xFFFFu) | (r[1] << 16);
  o.y = (r[2] & 0xFFFFu) | (r[3] << 16);
  o.z = (r[4] & 0xFFFFu) | (r[5] << 16);
  o.w = (r[6] & 0xFFFFu) | (r[7] << 16);
  *(uint4*)(rank16 + base) = o;
  if (t == 255) part[blockIdx.x] = s[255];
}

__global__ void k_scanB(unsigned* __restrict__ part, Hdr* h) {
  __shared__ unsigned s[256];
  int t = threadIdx.x;
  int lo = t * CHUNK;
  unsigned local[CHUNK];
  unsigned sum = 0;
  #pragma unroll
  for (int k = 0; k < CHUNK; ++k) {
    int j = lo + k;
    local[k] = (j < PBLK) ? part[j] : 0u;
    sum += local[k];
  }
  s[t] = sum; __syncthreads();
  for (int off = 1; off < 256; off <<= 1) {
    unsigned v = (t >= off) ? s[t - off] : 0u;
    __syncthreads();
    s[t] += v;
    __syncthreads();
  }
  unsigned run = s[t] - sum;
  #pragma unroll
  for (int k = 0; k < CHUNK; ++k) {
    int j = lo + k;
    if (j < PBLK) part[j] = run;
    run += local[k];
  }
  if (t == 255) h->M = (int)s[255];
}

// 9 word-probes per point (dz-triple = 3 consecutive bits); append hits
// (i,r,w) to global list + one count-atomic per hit.
__global__ void k_probe(const float4* __restrict__ pts, int n,
                        const Hdr* __restrict__ h,
                        const unsigned* __restrict__ bm,
                        const unsigned short* __restrict__ rank16,
                        const unsigned* __restrict__ part,
                        int* __restrict__ hit_i, int* __restrict__ hit_r,
                        float* __restrict__ hit_w,
                        unsigned* __restrict__ g_cnt,
                        float* __restrict__ acc) {
  __shared__ int s_cnt;
  __shared__ int s_base;
  __shared__ int   s_i[HCAP];
  __shared__ int   s_r[HCAP];
  __shared__ float s_w[HCAP];
  if (threadIdx.x == 0) s_cnt = 0;
  __syncthreads();
  int i = blockIdx.x * 256 + threadIdx.x;
  const float gg = 0.4f * 0.4f;
  const float decay2 = (gg + gg + gg) * 0.25f;   // bitwise == ref
  if (i < n) {
    float4 p = pts[i];
    int c[4];
    coors_from(p, h->pc_min[0], h->pc_min[1], h->pc_min[2], h->pc_min[3], c);
    int d1 = h->dims[1], d2 = h->dims[2], d3 = h->dims[3];
    float m1 = h->pc_min[1], m2 = h->pc_min[2], m3 = h->pc_min[3];
    #pragma unroll
    for (int dx = -1; dx <= 1; ++dx) {
      #pragma unroll
      for (int dy = -1; dy <= 1; ++dy) {
        int n1 = c[1] + dx, n2 = c[2] + dy;
        int kc = ((c[0] * d1 + n1) * d2 + n2) * d3 + c[3];  // dz = 0
        unsigned k = (unsigned)kc;
        if (k < 1u || k + 1u >= WMAX * 32u) continue;       // safety
        unsigned w = k >> 5, b = k & 31u;
        unsigned cur = bm[w];
        unsigned tri;
        if (b == 0u)
          tri = (bm[w - 1] >> 31) | ((cur & 3u) << 1);
        else if (b == 31u)
          tri = ((cur >> 30) & 3u) | ((bm[w + 1] & 1u) << 2);
        else
          tri = (cur >> (b - 1)) & 7u;
        if (!tri) continue;
        #pragma unroll
        for (int j = 0; j < 3; ++j) {
          if (!((tri >> j) & 1u)) continue;
          unsigned kj = k + (unsigned)(j - 1);
          unsigned wj = kj >> 5, bj = kj & 31u;
          unsigned word = (wj == w) ? cur : bm[wj];
          int r = (int)(part[kj >> 16] + (unsigned)rank16[wj] +
                        __popc(word & ((1u << bj) - 1u)));
          int n3 = c[3] + (j - 1);
          float cx = (float)(n1 - 1) * 0.4f + m1;
          float cy = (float)(n2 - 1) * 0.4f + m2;
          float cz = (float)(n3 - 1) * 0.4f + m3;
          float ex = p.y - cx, ey = p.z - cy, ez = p.w - cz;
          float dd = ex * ex + ey * ey + ez * ez;
          float wgt = expf(-dd / decay2);
          int pos = atomicAdd(&s_cnt, 1);
          if (pos < HCAP) {
            s_i[pos] = i; s_r[pos] = r; s_w[pos] = wgt;
          } else {
            direct_accum(acc, r, wgt, p);       // LDS overflow (rare)
          }
        }
      }
    }
  }
  __syncthreads();
  int cnt = min(s_cnt, HCAP);
  if (threadIdx.x == 0) s_base = (int)atomicAdd(g_cnt, (unsigned)cnt);
  __syncthreads();
  int base = s_base;
  for (int j = threadIdx.x; j < cnt; j += 256) {
    int gpos = base + j;
    int r = s_r[j];
    if (gpos < HITCAP) {
      hit_i[gpos] = s_i[j];
      hit_r[gpos] = r;
      hit_w[gpos] = s_w[j];
      atomicAdd((unsigned*)(acc + (size_t)r * 12 + 11), 1u);
    } else {
      direct_accum(acc, r, s_w[j], pts[s_i[j]]);  // overflow (rare)
    }
  }
}

// single-contributor voxels (~95%) -> plain float4 stores; else atomicAdd.
__global__ void k_drain(const float4* __restrict__ pts,
                        const int* __restrict__ hit_i,
                        const int* __restrict__ hit_r,
                        const float* __restrict__ hit_w,
                        const unsigned* __restrict__ g_cnt,
                        float* __restrict__ acc) {
  int total = min((int)*g_cnt, HITCAP);
  for (int j = blockIdx.x * 256 + threadIdx.x; j < total;
       j += gridDim.x * 256) {
    int r = hit_r[j];
    float wgt = hit_w[j];
    float4 q = pts[hit_i[j]];
    float* a = acc + (size_t)r * 12;
    unsigned c = *(const unsigned*)(a + 11);
    if (c == 1u) {
      float4 v0 = {wgt, wgt * q.x, wgt * q.y, wgt * q.z};
      float4 v1 = {wgt * q.w, wgt * q.y * q.y, wgt * q.y * q.z,
                   wgt * q.y * q.w};
      float4 v2 = {wgt * q.z * q.z, wgt * q.z * q.w, wgt * q.w * q.w, 0.0f};
      float4* av = (float4*)a;
      av[0] = v0; av[1] = v1; av[2] = v2;
    } else {
      atomicAdd(a + 0, wgt);
      atomicAdd(a + 1, wgt * q.x);
      atomicAdd(a + 2, wgt * q.y);
      atomicAdd(a + 3, wgt * q.z);
      atomicAdd(a + 4, wgt * q.w);
      atomicAdd(a + 5, wgt * q.y * q.y);
      atomicAdd(a + 6, wgt * q.y * q.z);
      atomicAdd(a + 7, wgt * q.y * q.w);
      atomicAdd(a + 8, wgt * q.z * q.z);
      atomicAdd(a + 9, wgt * q.z * q.w);
      atomicAdd(a + 10, wgt * q.w * q.w);
    }
  }
}

__global__ void k_finalize(const Hdr* __restrict__ h,
                           const float* __restrict__ acc,
                           float* __restrict__ out_mu,
                           float* __restrict__ out_R, int n) {
  int i = blockIdx.x * 256 + threadIdx.x;
  if (i >= n) return;
  const float4* av = (const float4*)(acc + (size_t)i * 12);
  float4 v0 = av[0], v1 = av[1], v2 = av[2];
  float ws = v0.x;
  bool ok = (i < h->M) && (ws > 0.0f);
  jacobi_out(ws, v0, v1, v2, ok, out_mu + (size_t)i * 4,
             out_R + (size_t)i * 9);
}

// ============================================================================
extern "C" void kernel_launch(void* const* d_in, const int* in_sizes, int n_in,
                              void* d_out, int out_size, void* d_ws,
                              size_t ws_size, hipStream_t stream) {
  const float4* pts = (const float4*)d_in[0];
  int n = in_sizes[0] / 4;
  float* out = (float*)d_out;
  float* outR = out + (size_t)4 * n;

  char* ws = (char*)d_ws;
  Hdr* hdr = (Hdr*)ws;
  size_t off = 256;
  unsigned* mmpart = (unsigned*)(ws + off);      off += (size_t)MMB * 8 * 4;
  unsigned* bm = (unsigned*)(ws + off);          off += (size_t)WMAX * 4;
  unsigned short* rank16 = (unsigned short*)(ws + off); off += (size_t)WMAX * 2;
  unsigned* part = (unsigned*)(ws + off);        off += 4096 * 4;
  unsigned* g_cnt = (unsigned*)(ws + off);       off += 256;
  int* hit_i = (int*)(ws + off);                 off += (size_t)HITCAP * 4;
  int* hit_r = (int*)(ws + off);                 off += (size_t)HITCAP * 4;
  float* hit_w = (float*)(ws + off);             off += (size_t)HITCAP * 4;
  float* acc = (float*)(ws + off);               // n * 12 floats
  size_t needed = off + (size_t)n * 12 * 4;
  if (ws_size < needed) return;

  int nb = (n + 255) / 256;
  k_zero_minmax<<<MMB, 256, 0, stream>>>(pts, n, mmpart, bm, acc, g_cnt);
  k_prep<<<1, 256, 0, stream>>>(mmpart, hdr, MMB);
  k_mark<<<nb, 256, 0, stream>>>(pts, n, hdr, bm);
  k_scanA<<<PBLK, 256, 0, stream>>>(bm, rank16, part);
  k_scanB<<<1, 256, 0, stream>>>(part, hdr);
  k_probe<<<nb, 256, 0, stream>>>(pts, n, hdr, bm, rank16, part,
                                  hit_i, hit_r, hit_w, g_cnt, acc);
  k_drain<<<512, 256, 0, stream>>>(pts, hit_i, hit_r, hit_w, g_cnt, acc);
  k_finalize<<<nb, 256, 0, stream>>>(hdr, acc, out, outR, n);
}